// Round 2
// baseline (580.512 us; speedup 1.0000x reference)
//
#include <hip/hip_runtime.h>
#include <hip/hip_bf16.h>

// Correlation layer: out[b, i*41+j, y, x] = (1/576) * sum_c in1[b,c,y,x]*in2[b,c,y-dy,x-dx]
// dx = 2i-20, dy = 2j-20. b=4, c=64, h=96, w=160, D=41. Output 413 MB fp32 -> write-bound.
// R2: no in2 LDS staging (rows are L1/L2-hot), wave w owns N-tile nt=w, A-frag loaded
// once per M-tile, nontemporal output stores, XCD-affine grid swizzle (x=(b,y), y=j).

#define B_ 4
#define C_ 64
#define H_ 96
#define W_ 160
#define DD 41
#define HW_ (H_*W_)
#define GS 161           // gd row stride: 161 % 32 == 1 -> conflict-free scatter & read

typedef __bf16 bf16x8 __attribute__((ext_vector_type(8)));
typedef float  f32x4  __attribute__((ext_vector_type(4)));

// ---------------- Pass 1: NCHW fp32 -> NHWC bf16 ----------------
__global__ void to_nhwc(const float* __restrict__ s1, const float* __restrict__ s2,
                        ushort* __restrict__ d1, ushort* __restrict__ d2) {
    int p = blockIdx.x * 256 + threadIdx.x;            // pixel id in [0, B*H*W)
    const float* src = blockIdx.y ? s2 : s1;
    ushort* dst = blockIdx.y ? d2 : d1;
    int b = p / HW_;
    int rem = p - b * HW_;
    const float* sp = src + (size_t)b * (C_ * HW_) + rem;
    ushort tmp[C_];
#pragma unroll
    for (int c = 0; c < C_; ++c) {
        union { float f; unsigned u; } uu;
        uu.f = __builtin_nontemporal_load(&sp[(size_t)c * HW_]);  // read-once fp32
        unsigned r = uu.u + 0x7FFF + ((uu.u >> 16) & 1);          // RNE to bf16
        tmp[c] = (ushort)(r >> 16);
    }
    uint4* dp = (uint4*)(dst + (size_t)p * C_);
#pragma unroll
    for (int k = 0; k < 8; ++k) dp[k] = ((uint4*)tmp)[k];        // keep in L2 (reused)
}

// ---------------- Pass 2: correlation ----------------
__global__ __launch_bounds__(256, 4) void corr_kernel(const ushort* __restrict__ in1w,
                                                      const ushort* __restrict__ in2w,
                                                      float* __restrict__ out) {
    __shared__ float gd[DD * GS];         // banded Gram, 26.4 KB -> 4+ blocks/CU

    const int bx = blockIdx.x;            // (b,y): all 41 j-blocks of a row share
    const int j  = blockIdx.y;            // linear-id mod 8 -> same XCD L2
    const int b  = bx / H_;
    const int y  = bx - b * H_;
    const int lane = threadIdx.x & 63;
    const int w    = threadIdx.x >> 6;    // wave id = N-tile nt
    const int quad = lane >> 4;
    const int l15  = lane & 15;
    const int y2 = y + 20 - 2 * j;
    const bool valid_row = (y2 >= 0) && (y2 < H_);

    if (valid_row) {
        const ushort* a_base = in1w + (size_t)((b * H_ + y) * W_) * C_;
        const ushort* b_base = in2w + (size_t)((b * H_ + y2) * W_) * C_;
        // 10 M-tiles (5 even-x, 5 odd-x); wave w does N-tile nt=w for each.
#pragma unroll 2
        for (int mi = 0; mi < 10; ++mi) {
            const int par = (mi >= 5) ? 1 : 0;
            const int x0  = (mi - 5 * par) * 32;          // 0,32,64,96,128
            // A fragment: A[m=l15][k=quad*8+jj], x = x0+par+2*m  (16 lines/instr, L1-hot)
            const int xa = x0 + par + 2 * l15;
            const bf16x8* aptr = (const bf16x8*)(const void*)(a_base + xa * C_ + quad * 8);
            bf16x8 a0 = aptr[0];                          // k 0..31
            bf16x8 a1 = aptr[4];                          // k 32..63
            // B fragment: B[k][n=l15], u = x0+par-60+32*w+2*n (same parity as x)
            const int u = x0 + par - 60 + 32 * w + 2 * l15;
            bf16x8 b0 = {}, b1 = {};
            if (u >= 0 && u < W_) {
                const bf16x8* bptr = (const bf16x8*)(const void*)(b_base + u * C_ + quad * 8);
                b0 = bptr[0];
                b1 = bptr[4];
            }
            f32x4 acc = {};
            acc = __builtin_amdgcn_mfma_f32_16x16x32_bf16(a0, b0, acc, 0, 0, 0);
            acc = __builtin_amdgcn_mfma_f32_16x16x32_bf16(a1, b1, acc, 0, 0, 0);
            // scatter band: C/D layout col(n)=l15, row(m)=quad*4+r
            // i = (x-u+20)/2 = mx - n - 16*nt + 40; each (i,x) written exactly once
#pragma unroll
            for (int r = 0; r < 4; ++r) {
                const int mx = quad * 4 + r;
                const int i  = mx - l15 - 16 * w + 40;
                if (i >= 0 && i <= 40) {
                    gd[i * GS + x0 + par + 2 * mx] = acc[r];
                }
            }
        }
        __syncthreads();
    }

    // ---- output pass: out[b, i*41+j, y, 0..159], coalesced, nontemporal (write-once)
    const float scale = 1.0f / 576.0f;
    for (int i = w; i < DD; i += 4) {
        float* op = out + ((size_t)(b * (DD * DD) + i * DD + j) * H_ + y) * W_;
        if (valid_row) {
            __builtin_nontemporal_store(gd[i * GS + lane] * scale, &op[lane]);
            __builtin_nontemporal_store(gd[i * GS + lane + 64] * scale, &op[lane + 64]);
            if (lane < 32)
                __builtin_nontemporal_store(gd[i * GS + lane + 128] * scale, &op[lane + 128]);
        } else {
            __builtin_nontemporal_store(0.0f, &op[lane]);
            __builtin_nontemporal_store(0.0f, &op[lane + 64]);
            if (lane < 32)
                __builtin_nontemporal_store(0.0f, &op[lane + 128]);
        }
    }
}

extern "C" void kernel_launch(void* const* d_in, const int* in_sizes, int n_in,
                              void* d_out, int out_size, void* d_ws, size_t ws_size,
                              hipStream_t stream) {
    const float* in1 = (const float*)d_in[0];
    const float* in2 = (const float*)d_in[1];
    float* out = (float*)d_out;
    ushort* w1 = (ushort*)d_ws;                      // 4*96*160*64 bf16 = 7.86 MB
    ushort* w2 = w1 + (size_t)B_ * H_ * W_ * C_;
    to_nhwc<<<dim3((B_ * HW_) / 256, 2), 256, 0, stream>>>(in1, in2, w1, w2);
    // grid: x = (b,y) so the 41 j-blocks of one row share an XCD; y = j
    corr_kernel<<<dim3(B_ * H_, DD), 256, 0, stream>>>(w1, w2, out);
}